// Round 16
// baseline (223.379 us; speedup 1.0000x reference)
//
#include <hip/hip_runtime.h>
#include <hip/hip_bf16.h>

#define NH  12
#define HD  64
#define DIM 768
#define SEQ 2048
#define NB  4
#define MM  (NB*SEQ)   // 8192 rows
#define NKB (SEQ/64)   // 32 key-blocks per head
#define N4X (MM*DIM/4)     // 1572864 float4-groups in x
#define N4W (DIM*DIM/4)    // 147456 float4-groups per weight

typedef short    v8s  __attribute__((ext_vector_type(8)));   // 8 x bf16 (4 VGPRs)
typedef float    v4f  __attribute__((ext_vector_type(4)));
typedef float    v16f __attribute__((ext_vector_type(16)));
typedef unsigned v4u  __attribute__((ext_vector_type(4)));

#if __has_builtin(__builtin_amdgcn_exp2f)
#define EXP2(x) __builtin_amdgcn_exp2f(x)
#else
#define EXP2(x) __builtin_exp2f(x)
#endif

// round-to-nearest-even f32 -> bf16
static __device__ __forceinline__ unsigned short f2b(float f) {
    unsigned int u = __float_as_uint(f);
    return (unsigned short)((u + 0x7FFFu + ((u >> 16) & 1u)) >> 16);
}
// single-instruction pack: dst = bf16(lo) | bf16(hi)<<16 (RNE)
static __device__ __forceinline__ unsigned cvtpk(float lo, float hi) {
    unsigned r;
    asm("v_cvt_pk_bf16_f32 %0, %1, %2" : "=v"(r) : "v"(lo), "v"(hi));
    return r;
}
// async global->LDS DMA, 16B/lane; LDS base wave-uniform, writes base+lane*16
static __device__ __forceinline__ void g2l16(const unsigned short* g, unsigned short* l) {
    __builtin_amdgcn_global_load_lds(
        (const __attribute__((address_space(1))) void*)g,
        (__attribute__((address_space(3))) void*)l, 16, 0, 0);
}

// One merged cast kernel: items [0, N4X) = x; then 4 weight ranges of N4W.
// Exact-fit 1D grid (8448 blocks x 256 thr), no idle blocks.
__global__ void cast_all(const float* __restrict__ x,
                         const float* __restrict__ qw, const float* __restrict__ kw,
                         const float* __restrict__ vw, const float* __restrict__ ow,
                         unsigned short* __restrict__ xb,
                         unsigned short* __restrict__ wqb, unsigned short* __restrict__ wkb,
                         unsigned short* __restrict__ wvb, unsigned short* __restrict__ wob)
{
    int i = blockIdx.x * blockDim.x + threadIdx.x;
    const float* in; unsigned short* out; int idx;
    if (i < N4X) {
        in = x; out = xb; idx = i;
    } else {
        int j = i - N4X;
        int s = j / N4W;           // 0..3 (compiler magic-mul)
        idx = j - s * N4W;
        switch (s) {
            case 0:  in = qw; out = wqb; break;
            case 1:  in = kw; out = wkb; break;
            case 2:  in = vw; out = wvb; break;
            default: in = ow; out = wob; break;
        }
    }
    float4 v = reinterpret_cast<const float4*>(in)[idx];
    ushort4 o;
    o.x = f2b(v.x); o.y = f2b(v.y); o.z = f2b(v.z); o.w = f2b(v.w);
    reinterpret_cast<ushort4*>(out)[idx] = o;
}

// Merged QKV, R16: 64-ROW TILES for 16 waves/CU. qkv was the last unmeasured
// chunk (~60-65us, never in top-5) and shares attn's latency-bound structure
// at 12 waves/CU -- but unlike attn it has VGPR headroom: acc[3][2][2] ~94
// VGPR < 128 => the m69 occupancy step allows 16 waves/CU. Halving the M-tile
// doubles the grid (1536 blocks) -> 4 resident blocks/CU (+33% TLP), LDS
// 32 KB. Fragment/swizzle patterns identical to the verified 128-row version;
// epilogue deltas derived: kh=wm, l31k=i*16+quad*4, V frag slot=wm*2+i.
// grid (128,12): 128 % 8 == 0 so all 12 heads sharing an A-tile land on the
// same XCD already -- do NOT add a swizzle. Single-buffer staging (dbuf
// proved neutral R13). Cross-kernel fusion UNSAFE (R14: grid.sync does not
// make cross-XCD L2 writes visible to global_load_lds readers).
__global__ __launch_bounds__(256, 4) void gemm_qkv(
    const unsigned short* __restrict__ A,
    const unsigned short* __restrict__ Wq,
    const unsigned short* __restrict__ Wk,
    const unsigned short* __restrict__ Wv,
    const float* __restrict__ bq,
    const float* __restrict__ bk,
    const float* __restrict__ bvp,
    unsigned short* __restrict__ Qb,
    unsigned short* __restrict__ Kfo,
    unsigned short* __restrict__ Vf)
{
    __shared__ __align__(16) unsigned short As[64 * 64];       // 8 KB
    __shared__ __align__(16) unsigned short Bs[3][64 * 64];    // 24 KB

    const int tid  = threadIdx.x;
    const int w    = tid >> 6, lane = tid & 63;
    const int quad = lane >> 4, l16 = lane & 15;
    const int wm   = w & 1,  wn = w >> 1;
    const int lane8 = lane >> 3, sc = lane & 7;
    const int m0   = blockIdx.x * 64;
    const int h    = blockIdx.y;
    const int n0   = h * 64;

    v4f acc[3][2][2];
    #pragma unroll
    for (int s = 0; s < 3; ++s)
        #pragma unroll
        for (int i = 0; i < 2; ++i)
            #pragma unroll
            for (int j = 0; j < 2; ++j)
                acc[s][i][j] = v4f{0.f, 0.f, 0.f, 0.f};

    for (int kb = 0; kb < DIM; kb += 64) {
        __syncthreads();
        // A: 64 rows, 8 DMA calls (8 rows each), 2 per wave
        #pragma unroll
        for (int t = 0; t < 2; ++t) {
            int r8 = w * 16 + t * 8;
            int r  = r8 + lane8;
            int gch = sc ^ (r & 7);
            g2l16(&A[(size_t)(m0 + r) * DIM + kb + gch * 8], &As[r8 * 64]);
        }
        // B: 3 x 64 rows, 24 calls, 6 per wave (identical to 128-row version)
        #pragma unroll
        for (int u = 0; u < 6; ++u) {
            int G = w * 6 + u;               // 0..23: set = G>>3, rowgrp = G&7
            int set = G >> 3, rg = G & 7;
            int row = rg * 8 + lane8;
            int gch = sc ^ (row & 7);
            const unsigned short* Wp = (set == 0) ? Wq : (set == 1) ? Wk : Wv;
            g2l16(&Wp[(size_t)(n0 + row) * DIM + kb + gch * 8], &Bs[set][rg * 8 * 64]);
        }
        __syncthreads();
        #pragma unroll
        for (int kk = 0; kk < 64; kk += 32) {
            int chb = kk >> 3;
            v8s a[2];
            #pragma unroll
            for (int i = 0; i < 2; ++i) {
                int m = wm * 32 + i * 16 + l16;
                a[i] = *reinterpret_cast<const v8s*>(
                    &As[m * 64 + (((chb + quad) ^ (m & 7)) << 3)]);
            }
            #pragma unroll
            for (int s = 0; s < 3; ++s) {
                v8s b[2];
                #pragma unroll
                for (int j = 0; j < 2; ++j) {
                    int n = wn * 32 + j * 16 + l16;
                    b[j] = *reinterpret_cast<const v8s*>(
                        &Bs[s][n * 64 + (((chb + quad) ^ (n & 7)) << 3)]);
                }
                #pragma unroll
                for (int i = 0; i < 2; ++i)
                    #pragma unroll
                    for (int j = 0; j < 2; ++j)
                        acc[s][i][j] = __builtin_amdgcn_mfma_f32_16x16x32_bf16(
                            a[i], b[j], acc[s][i][j], 0, 0, 0);
            }
        }
    }

    // ---- epilogues (rows m0 .. m0+63; local row = wm*32 + i*16 + quad*4 + r)
    // Q: [bh][seq][hd], pre-scaled by 1/8 * log2(e)
    #pragma unroll
    for (int i = 0; i < 2; ++i) {
        #pragma unroll
        for (int j = 0; j < 2; ++j) {
            int hd = wn * 32 + j * 16 + l16;
            float bias_v = bq[n0 + hd];
            #pragma unroll
            for (int r = 0; r < 4; ++r) {
                int gm = m0 + wm * 32 + i * 16 + quad * 4 + r;
                int bb = gm >> 11, sq = gm & (SEQ - 1);
                Qb[((size_t)(bb * NH + h) * SEQ + sq) * HD + hd] =
                    f2b((acc[0][i][j][r] + bias_v) * 0.1803368801f);
            }
        }
    }
    // K: fragment-native Kf[bh][t][kh*4+c][lane(=hdbit3*32 + key&31)][8]
    // local key = wm*32 + i*16 + quad*4 (+r)  =>  kh = wm, l31k = i*16+quad*4
    #pragma unroll
    for (int i = 0; i < 2; ++i) {
        #pragma unroll
        for (int j = 0; j < 2; ++j) {
            int hd = wn * 32 + j * 16 + l16;
            int c  = hd >> 4;              // = wn*2 + j
            int half_a = (l16 >> 3) & 1;   // hd bit 3
            int jj = l16 & 7;              // hd low 3 bits
            float bias_v = bk[n0 + hd];
            int gm0 = m0 + wm * 32 + i * 16 + quad * 4;
            int bb = gm0 >> 11, sk = gm0 & (SEQ - 1);
            int t = sk >> 6;
            int kh = wm;
            int l31k = i * 16 + quad * 4;                // + r below
            size_t frag = ((size_t)(bb * NH + h) * NKB + t) * 8 + kh * 4 + c;
            unsigned short* dst = &Kfo[frag * 512 + (half_a * 32 + l31k) * 8 + jj];
            #pragma unroll
            for (int r = 0; r < 4; ++r)
                dst[r * 8] = f2b(acc[1][i][j][r] + bias_v);
        }
    }
    // V: fragment-native Vf[bh][kbi][hb*4+c슬ot][lane][8]; key-slot = wm*2+i
    #pragma unroll
    for (int i = 0; i < 2; ++i) {
        #pragma unroll
        for (int j = 0; j < 2; ++j) {
            int hd = wn * 32 + j * 16 + l16;
            int hb = hd >> 5, l31v = hd & 31;
            float bias_v = bvp[n0 + hd];
            int gm0 = m0 + wm * 32 + i * 16 + quad * 4;
            int bb = gm0 >> 11, sk = gm0 & (SEQ - 1);
            int kbi = sk >> 6;
            int slot = wm * 2 + i;                       // 16-key group in tile
            int halfv = quad >> 1, j0 = (quad & 1) * 4;
            ushort4 pkv;
            pkv.x = f2b(acc[2][i][j][0] + bias_v);
            pkv.y = f2b(acc[2][i][j][1] + bias_v);
            pkv.z = f2b(acc[2][i][j][2] + bias_v);
            pkv.w = f2b(acc[2][i][j][3] + bias_v);
            size_t frag = ((size_t)(bb * NH + h) * NKB + kbi) * 8 + hb * 4 + slot;
            *reinterpret_cast<ushort4*>(
                &Vf[frag * 512 + (halfv * 32 + l31v) * 8 + j0]) = pkv;
        }
    }
}

// Output projection: 128x64 tiles, grid (64, 12) = 768 blocks = 3 WG/CU even.
__global__ __launch_bounds__(256, 3) void gemm_o(
    const unsigned short* __restrict__ A,
    const unsigned short* __restrict__ W,
    const float* __restrict__ bias,
    float* __restrict__ out)
{
    __shared__ __align__(16) unsigned short As[128 * 64];   // 16 KB
    __shared__ __align__(16) unsigned short Bs[64 * 64];    // 8 KB

    const int tid  = threadIdx.x;
    const int w    = tid >> 6, lane = tid & 63;
    const int quad = lane >> 4, l16 = lane & 15;
    const int wm   = w & 1,  wn = w >> 1;
    const int lane8 = lane >> 3, sc = lane & 7;
    const int m0  = blockIdx.x * 128;
    const int n0l = blockIdx.y * 64;

    v4f acc[4][2];
    #pragma unroll
    for (int i = 0; i < 4; ++i)
        #pragma unroll
        for (int j = 0; j < 2; ++j)
            acc[i][j] = v4f{0.f, 0.f, 0.f, 0.f};

    for (int kb = 0; kb < DIM; kb += 64) {
        __syncthreads();
        #pragma unroll
        for (int t = 0; t < 4; ++t) {
            int r8 = w * 32 + t * 8;
            int r  = r8 + lane8;
            int gch = sc ^ (r & 7);
            g2l16(&A[(size_t)(m0 + r) * DIM + kb + gch * 8], &As[r8 * 64]);
        }
        #pragma unroll
        for (int t = 0; t < 2; ++t) {
            int r8 = (w * 2 + t) * 8;
            int r  = r8 + lane8;
            int gch = sc ^ (r & 7);
            g2l16(&W[(size_t)(n0l + r) * DIM + kb + gch * 8], &Bs[r8 * 64]);
        }
        __syncthreads();
        #pragma unroll
        for (int kk = 0; kk < 64; kk += 32) {
            v8s a[4], b[2];
            int chb = kk >> 3;
            #pragma unroll
            for (int i = 0; i < 4; ++i) {
                int m = wm * 64 + i * 16 + l16;
                a[i] = *reinterpret_cast<const v8s*>(
                    &As[m * 64 + (((chb + quad) ^ (m & 7)) << 3)]);
            }
            #pragma unroll
            for (int j = 0; j < 2; ++j) {
                int n = wn * 32 + j * 16 + l16;
                b[j] = *reinterpret_cast<const v8s*>(
                    &Bs[n * 64 + (((chb + quad) ^ (n & 7)) << 3)]);
            }
            #pragma unroll
            for (int i = 0; i < 4; ++i)
                #pragma unroll
                for (int j = 0; j < 2; ++j)
                    acc[i][j] = __builtin_amdgcn_mfma_f32_16x16x32_bf16(a[i], b[j], acc[i][j], 0, 0, 0);
        }
    }

    #pragma unroll
    for (int i = 0; i < 4; ++i) {
        #pragma unroll
        for (int j = 0; j < 2; ++j) {
            int gn = n0l + wn * 32 + j * 16 + l16;
            float bias_v = bias[gn];
            #pragma unroll
            for (int r = 0; r < 4; ++r) {
                int gm = m0 + wm * 64 + i * 16 + quad * 4 + r;
                out[(size_t)gm * DIM + gn] = acc[i][j][r] + bias_v;
            }
        }
    }
}

// ---------------------------------------------------------------------------
// Transposed flash attention (best verified structure, 66-67us, absmax
// 4.88e-4): LDS double-buffer for both K and V staged once per block via
// global_load_lds (kills the 4x redundant per-wave L2 streams), one plain
// __syncthreads per tile, permlane32_swap partner exchange, split PV
// accumulators, cvtpk packing, XCD-swizzled blockIdx (FETCH 18.5 MB).
// Plateaued at the 3-wave/SIMD interleave limit.
// ---------------------------------------------------------------------------
__global__ __launch_bounds__(256, 3) void attn(
    const unsigned short* __restrict__ Q,
    const unsigned short* __restrict__ Kf,
    const unsigned short* __restrict__ Vf,
    unsigned short* __restrict__ ctx)
{
    __shared__ __align__(16) unsigned short Ks[2][8 * 512];   // 16 KB
    __shared__ __align__(16) unsigned short Vs[2][8 * 512];   // 16 KB

    const int tid  = threadIdx.x;
    const int w    = tid >> 6, lane = tid & 63;
    const int l31  = lane & 31, half = lane >> 5;

    // XCD swizzle: 768 blocks, 8 XCDs -> XCD k owns bh [6k, 6k+6) x 16 q-tiles
    const int lblk = blockIdx.y * 16 + blockIdx.x;       // gridDim.x == 16
    const int vblk = (lblk & 7) * 96 + (lblk >> 3);
    const int bh   = vblk >> 4;
    const int b    = bh / NH, h = bh % NH;
    const int q0   = (vblk & 15) * 128 + w * 32;

    const unsigned short* Qp = Q  + ((size_t)bh * SEQ + q0) * HD;
    const unsigned short* Kh = Kf + (size_t)bh * (NKB * 8 * 512);
    const unsigned short* Vh = Vf + (size_t)bh * (NKB * 8 * 512);

    // Q B-frag: B[n=q=l31][k = c*16 + half*8 + j] (pre-scaled by 0.125*log2e)
    v8s bq[4];
    #pragma unroll
    for (int c = 0; c < 4; ++c)
        bq[c] = *reinterpret_cast<const v8s*>(&Qp[l31 * HD + c * 16 + half * 8]);

    // wave w stages K frags {2w, 2w+1} and V frags {2w, 2w+1} of each tile
    #define STAGE(it_, buf_)                                                   \
        do {                                                                   \
            _Pragma("unroll")                                                  \
            for (int t = 0; t < 2; ++t) {                                      \
                int g = w * 2 + t;                                             \
                g2l16(&Kh[((size_t)(it_) * 8 + g) * 512 + lane * 8],           \
                      &Ks[buf_][g * 512]);                                     \
                g2l16(&Vh[((size_t)(it_) * 8 + g) * 512 + lane * 8],           \
                      &Vs[buf_][g * 512]);                                     \
            }                                                                  \
        } while (0)

    STAGE(0, 0);

    v16f o0a, o0b, o1a, o1b, Z;
    #pragma unroll
    for (int i = 0; i < 16; ++i) {
        o0a[i] = 0.f; o0b[i] = 0.f; o1a[i] = 0.f; o1b[i] = 0.f; Z[i] = 0.f;
    }
    float li = 0.f;

    int cur = 0;
    for (int it = 0; it < NKB; ++it) {
        __syncthreads();                       // certifies STAGE(it) block-wide
        if (it + 1 < NKB) STAGE(it + 1, cur ^ 1);

        const unsigned short* Kb_ = Ks[cur];
        const unsigned short* Vb_ = Vs[cur];

        // S^T[key][q]: two independent 4-deep MFMA chains (keys 0..31 / 32..63)
        v16f s0, s1;
        {
            v8s k0 = *reinterpret_cast<const v8s*>(&Kb_[lane * 8]);
            v8s k1 = *reinterpret_cast<const v8s*>(&Kb_[4 * 512 + lane * 8]);
            s0 = __builtin_amdgcn_mfma_f32_32x32x16_bf16(k0, bq[0], Z, 0, 0, 0);
            s1 = __builtin_amdgcn_mfma_f32_32x32x16_bf16(k1, bq[0], Z, 0, 0, 0);
            #pragma unroll
            for (int c = 1; c < 4; ++c) {
                v8s kc0 = *reinterpret_cast<const v8s*>(&Kb_[(size_t)c * 512 + lane * 8]);
                v8s kc1 = *reinterpret_cast<const v8s*>(&Kb_[(size_t)(4 + c) * 512 + lane * 8]);
                s0 = __builtin_amdgcn_mfma_f32_32x32x16_bf16(kc0, bq[c], s0, 0, 0, 0);
                s1 = __builtin_amdgcn_mfma_f32_32x32x16_bf16(kc1, bq[c], s1, 0, 0, 0);
            }
        }

        // exp2 + lane-local li + pack key-pairs (1 instr per pair via cvt_pk)
        unsigned pk[8][2];
        #pragma unroll
        for (int g = 0; g < 4; ++g) {
            float e0 = EXP2(s0[4*g+0]), e1 = EXP2(s0[4*g+1]);
            float e2 = EXP2(s0[4*g+2]), e3 = EXP2(s0[4*g+3]);
            li += (e0 + e1) + (e2 + e3);
            pk[g][0] = cvtpk(e0, e1);
            pk[g][1] = cvtpk(e2, e3);
            float f0 = EXP2(s1[4*g+0]), f1 = EXP2(s1[4*g+1]);
            float f2 = EXP2(s1[4*g+2]), f3 = EXP2(s1[4*g+3]);
            li += (f0 + f1) + (f2 + f3);
            pk[4+g][0] = cvtpk(f0, f1);
            pk[4+g][1] = cvtpk(f2, f3);
        }

        // P^T B-frags via v_permlane32_swap_b32 (R8-verified); V from LDS.
        #pragma unroll
        for (int cp = 0; cp < 4; ++cp) {
            unsigned a0 = pk[2*cp][0],   a1 = pk[2*cp][1];
            unsigned b0 = pk[2*cp+1][0], b1 = pk[2*cp+1][1];
            asm("v_permlane32_swap_b32 %0, %1" : "+v"(a0), "+v"(b0));
            asm("v_permlane32_swap_b32 %0, %1" : "+v"(a1), "+v"(b1));
            v4u fw;
            fw.x = a0; fw.y = a1; fw.z = b0; fw.w = b1;
            v8s pf = __builtin_bit_cast(v8s, fw);
            v8s v0 = *reinterpret_cast<const v8s*>(&Vb_[(size_t)cp * 512 + lane * 8]);
            v8s v1 = *reinterpret_cast<const v8s*>(&Vb_[(size_t)(4 + cp) * 512 + lane * 8]);
            if (cp < 2) {
                o0a = __builtin_amdgcn_mfma_f32_32x32x16_bf16(v0, pf, o0a, 0, 0, 0);
                o1a = __builtin_amdgcn_mfma_f32_32x32x16_bf16(v1, pf, o1a, 0, 0, 0);
            } else {
                o0b = __builtin_amdgcn_mfma_f32_32x32x16_bf16(v0, pf, o0b, 0, 0, 0);
                o1b = __builtin_amdgcn_mfma_f32_32x32x16_bf16(v1, pf, o1b, 0, 0, 0);
            }
        }

        cur ^= 1;
    }
    #undef STAGE

    // li total = own 32 keys + partner's 32 keys (same q)
    float inv = 1.0f / (li + __shfl_xor(li, 32));

    // O^T: lane holds q = q0+l31; rows hd = (reg&3)+8*(reg>>2)+4*half (+32 for o1)
    const int q = q0 + l31;
    size_t base = ((size_t)(b * SEQ + q)) * DIM + h * HD;
    #pragma unroll
    for (int g = 0; g < 4; ++g) {
        int hd0 = 8 * g + 4 * half;
        uint2 u0, u1;
        u0.x = cvtpk((o0a[4*g+0] + o0b[4*g+0]) * inv, (o0a[4*g+1] + o0b[4*g+1]) * inv);
        u0.y = cvtpk((o0a[4*g+2] + o0b[4*g+2]) * inv, (o0a[4*g+3] + o0b[4*g+3]) * inv);
        u1.x = cvtpk((o1a[4*g+0] + o1b[4*g+0]) * inv, (o1a[4*g+1] + o1b[4*g+1]) * inv);
        u1.y = cvtpk((o1a[4*g+2] + o1b[4*g+2]) * inv, (o1a[4*g+3] + o1b[4*g+3]) * inv);
        *reinterpret_cast<uint2*>(&ctx[base + hd0])      = u0;
        *reinterpret_cast<uint2*>(&ctx[base + 32 + hd0]) = u1;
    }
}

extern "C" void kernel_launch(void* const* d_in, const int* in_sizes, int n_in,
                              void* d_out, int out_size, void* d_ws, size_t ws_size,
                              hipStream_t stream) {
    const float* x  = (const float*)d_in[0];
    const float* qw = (const float*)d_in[1]; const float* qb = (const float*)d_in[2];
    const float* kw = (const float*)d_in[3]; const float* kb = (const float*)d_in[4];
    const float* vw = (const float*)d_in[5]; const float* vb = (const float*)d_in[6];
    const float* ow = (const float*)d_in[7]; const float* ob = (const float*)d_in[8];
    float* out = (float*)d_out;

    char* ws = (char*)d_ws;
    size_t off = 0;
    auto alloc = [&](size_t bytes) -> unsigned short* {
        unsigned short* p = (unsigned short*)(ws + off);
        off += (bytes + 255) & ~(size_t)255;
        return p;
    };
    const size_t XB = (size_t)MM * DIM * 2;
    const size_t WB = (size_t)DIM * DIM * 2;
    const size_t QB = (size_t)NB * NH * SEQ * HD * 2;

    unsigned short* xb  = alloc(XB);
    unsigned short* wqb = alloc(WB);
    unsigned short* wkb = alloc(WB);
    unsigned short* wvb = alloc(WB);
    unsigned short* wob = alloc(WB);
    unsigned short* Qb  = alloc(QB);
    unsigned short* Kfb = alloc(QB);   // fragment-native K
    unsigned short* Vfb = alloc(QB);   // fragment-native V
    unsigned short* ctx = alloc(XB);

    const int nitems = N4X + 4 * N4W;            // 2162688, /256 = 8448 exact
    cast_all<<<nitems / 256, 256, 0, stream>>>(
        x, qw, kw, vw, ow, xb, wqb, wkb, wvb, wob);

    gemm_qkv<<<dim3(MM / 64, NH), 256, 0, stream>>>(
        xb, wqb, wkb, wvb, qb, kb, vb, Qb, Kfb, Vfb);

    attn<<<dim3(SEQ / 128, NB * NH), 256, 0, stream>>>(Qb, Kfb, Vfb, ctx);

    gemm_o<<<dim3(MM / 128, DIM / 64), 256, 0, stream>>>(ctx, wob, ob, out);
}

// Round 17
// 200.465 us; speedup vs baseline: 1.1143x; 1.1143x over previous
//
#include <hip/hip_runtime.h>
#include <hip/hip_bf16.h>

#define NH  12
#define HD  64
#define DIM 768
#define SEQ 2048
#define NB  4
#define MM  (NB*SEQ)   // 8192 rows
#define NKB (SEQ/64)   // 32 key-blocks per head
#define N4X (MM*DIM/4)     // 1572864 float4-groups in x
#define N4W (DIM*DIM/4)    // 147456 float4-groups per weight

typedef short    v8s  __attribute__((ext_vector_type(8)));   // 8 x bf16 (4 VGPRs)
typedef float    v4f  __attribute__((ext_vector_type(4)));
typedef float    v16f __attribute__((ext_vector_type(16)));
typedef unsigned v4u  __attribute__((ext_vector_type(4)));

#if __has_builtin(__builtin_amdgcn_exp2f)
#define EXP2(x) __builtin_amdgcn_exp2f(x)
#else
#define EXP2(x) __builtin_exp2f(x)
#endif

// round-to-nearest-even f32 -> bf16
static __device__ __forceinline__ unsigned short f2b(float f) {
    unsigned int u = __float_as_uint(f);
    return (unsigned short)((u + 0x7FFFu + ((u >> 16) & 1u)) >> 16);
}
// single-instruction pack: dst = bf16(lo) | bf16(hi)<<16 (RNE)
static __device__ __forceinline__ unsigned cvtpk(float lo, float hi) {
    unsigned r;
    asm("v_cvt_pk_bf16_f32 %0, %1, %2" : "=v"(r) : "v"(lo), "v"(hi));
    return r;
}
// async global->LDS DMA, 16B/lane; LDS base wave-uniform, writes base+lane*16
static __device__ __forceinline__ void g2l16(const unsigned short* g, unsigned short* l) {
    __builtin_amdgcn_global_load_lds(
        (const __attribute__((address_space(1))) void*)g,
        (__attribute__((address_space(3))) void*)l, 16, 0, 0);
}

// One merged cast kernel: items [0, N4X) = x; then 4 weight ranges of N4W.
// Exact-fit 1D grid (8448 blocks x 256 thr), no idle blocks.
__global__ void cast_all(const float* __restrict__ x,
                         const float* __restrict__ qw, const float* __restrict__ kw,
                         const float* __restrict__ vw, const float* __restrict__ ow,
                         unsigned short* __restrict__ xb,
                         unsigned short* __restrict__ wqb, unsigned short* __restrict__ wkb,
                         unsigned short* __restrict__ wvb, unsigned short* __restrict__ wob)
{
    int i = blockIdx.x * blockDim.x + threadIdx.x;
    const float* in; unsigned short* out; int idx;
    if (i < N4X) {
        in = x; out = xb; idx = i;
    } else {
        int j = i - N4X;
        int s = j / N4W;           // 0..3 (compiler magic-mul)
        idx = j - s * N4W;
        switch (s) {
            case 0:  in = qw; out = wqb; break;
            case 1:  in = kw; out = wkb; break;
            case 2:  in = vw; out = wvb; break;
            default: in = ow; out = wob; break;
        }
    }
    float4 v = reinterpret_cast<const float4*>(in)[idx];
    ushort4 o;
    o.x = f2b(v.x); o.y = f2b(v.y); o.z = f2b(v.z); o.w = f2b(v.w);
    reinterpret_cast<ushort4*>(out)[idx] = o;
}

// Merged QKV: grid (MM/128, NH), 128-row tiles (R16 proved 64-row tiles
// regress: halving the M-tile halves MFMA per staging phase while B staging
// stays constant -> 2x worse issue mix; B-reuse is load-bearing).
// K and V written FRAGMENT-NATIVE (MFMA A-frag layout): attn DMA-stages both
// linearly into LDS and reads conflict-free. Single-buffer staging (dbuf
// neutral, R13). grid (64,12): 64 % 8 == 0 so all 12 heads sharing an A-tile
// land on the same XCD already -- do NOT add a swizzle. Cross-kernel fusion
// UNSAFE (R14: grid.sync does not make cross-XCD L2 writes visible to
// global_load_lds readers -> stale data).
__global__ __launch_bounds__(256, 3) void gemm_qkv(
    const unsigned short* __restrict__ A,
    const unsigned short* __restrict__ Wq,
    const unsigned short* __restrict__ Wk,
    const unsigned short* __restrict__ Wv,
    const float* __restrict__ bq,
    const float* __restrict__ bk,
    const float* __restrict__ bvp,
    unsigned short* __restrict__ Qb,
    unsigned short* __restrict__ Kfo,
    unsigned short* __restrict__ Vf)
{
    __shared__ __align__(16) unsigned short As[128 * 64];      // 16 KB
    __shared__ __align__(16) unsigned short Bs[3][64 * 64];    // 24 KB

    const int tid  = threadIdx.x;
    const int w    = tid >> 6, lane = tid & 63;
    const int quad = lane >> 4, l16 = lane & 15;
    const int wm   = w & 1,  wn = w >> 1;
    const int lane8 = lane >> 3, sc = lane & 7;
    const int m0   = blockIdx.x * 128;
    const int h    = blockIdx.y;
    const int n0   = h * 64;

    v4f acc[3][4][2];
    #pragma unroll
    for (int s = 0; s < 3; ++s)
        #pragma unroll
        for (int i = 0; i < 4; ++i)
            #pragma unroll
            for (int j = 0; j < 2; ++j)
                acc[s][i][j] = v4f{0.f, 0.f, 0.f, 0.f};

    for (int kb = 0; kb < DIM; kb += 64) {
        __syncthreads();
        #pragma unroll
        for (int t = 0; t < 4; ++t) {
            int r8 = w * 32 + t * 8;
            int r  = r8 + lane8;
            int gch = sc ^ (r & 7);
            g2l16(&A[(size_t)(m0 + r) * DIM + kb + gch * 8], &As[r8 * 64]);
        }
        #pragma unroll
        for (int u = 0; u < 6; ++u) {
            int G = w * 6 + u;               // 0..23: set = G>>3, rowgrp = G&7
            int set = G >> 3, rg = G & 7;
            int row = rg * 8 + lane8;
            int gch = sc ^ (row & 7);
            const unsigned short* Wp = (set == 0) ? Wq : (set == 1) ? Wk : Wv;
            g2l16(&Wp[(size_t)(n0 + row) * DIM + kb + gch * 8], &Bs[set][rg * 8 * 64]);
        }
        __syncthreads();
        #pragma unroll
        for (int kk = 0; kk < 64; kk += 32) {
            int chb = kk >> 3;
            v8s a[4];
            #pragma unroll
            for (int i = 0; i < 4; ++i) {
                int m = wm * 64 + i * 16 + l16;
                a[i] = *reinterpret_cast<const v8s*>(
                    &As[m * 64 + (((chb + quad) ^ (m & 7)) << 3)]);
            }
            #pragma unroll
            for (int s = 0; s < 3; ++s) {
                v8s b[2];
                #pragma unroll
                for (int j = 0; j < 2; ++j) {
                    int n = wn * 32 + j * 16 + l16;
                    b[j] = *reinterpret_cast<const v8s*>(
                        &Bs[s][n * 64 + (((chb + quad) ^ (n & 7)) << 3)]);
                }
                #pragma unroll
                for (int i = 0; i < 4; ++i)
                    #pragma unroll
                    for (int j = 0; j < 2; ++j)
                        acc[s][i][j] = __builtin_amdgcn_mfma_f32_16x16x32_bf16(
                            a[i], b[j], acc[s][i][j], 0, 0, 0);
            }
        }
    }

    // ---- epilogues ----
    // Q: [bh][seq][hd], pre-scaled by 1/8 * log2(e)
    #pragma unroll
    for (int i = 0; i < 4; ++i) {
        #pragma unroll
        for (int j = 0; j < 2; ++j) {
            int hd = wn * 32 + j * 16 + l16;
            float bias_v = bq[n0 + hd];
            #pragma unroll
            for (int r = 0; r < 4; ++r) {
                int gm = m0 + wm * 64 + i * 16 + quad * 4 + r;
                int bb = gm >> 11, sq = gm & (SEQ - 1);
                Qb[((size_t)(bb * NH + h) * SEQ + sq) * HD + hd] =
                    f2b((acc[0][i][j][r] + bias_v) * 0.1803368801f);
            }
        }
    }
    // K: fragment-native Kf[bh][t][kh*4+c][lane(=hdbit3*32 + key&31)][8]
    #pragma unroll
    for (int i = 0; i < 4; ++i) {
        int kh = i >> 1;
        #pragma unroll
        for (int j = 0; j < 2; ++j) {
            int hd = wn * 32 + j * 16 + l16;
            int c  = hd >> 4;              // = wn*2 + j
            int half_a = (l16 >> 3) & 1;   // hd bit 3
            int jj = l16 & 7;              // hd low 3 bits
            float bias_v = bk[n0 + hd];
            int gm0 = m0 + wm * 64 + i * 16 + quad * 4;
            int bb = gm0 >> 11, sk = gm0 & (SEQ - 1);
            int t = sk >> 6;
            int l31k = (i & 1) * 16 + quad * 4;          // + r below
            size_t frag = ((size_t)(bb * NH + h) * NKB + t) * 8 + kh * 4 + c;
            unsigned short* dst = &Kfo[frag * 512 + (half_a * 32 + l31k) * 8 + jj];
            #pragma unroll
            for (int r = 0; r < 4; ++r)
                dst[r * 8] = f2b(acc[1][i][j][r] + bias_v);
        }
    }
    // V: fragment-native Vf[bh][kbi][hb*4+c][lane][8]
    #pragma unroll
    for (int i = 0; i < 4; ++i) {
        #pragma unroll
        for (int j = 0; j < 2; ++j) {
            int hd = wn * 32 + j * 16 + l16;
            int hb = hd >> 5, l31v = hd & 31;
            float bias_v = bvp[n0 + hd];
            int gm0 = m0 + wm * 64 + i * 16 + quad * 4;
            int bb = gm0 >> 11, sk = gm0 & (SEQ - 1);
            int kbi = sk >> 6;
            int halfv = quad >> 1, j0 = (quad & 1) * 4;
            ushort4 pkv;
            pkv.x = f2b(acc[2][i][j][0] + bias_v);
            pkv.y = f2b(acc[2][i][j][1] + bias_v);
            pkv.z = f2b(acc[2][i][j][2] + bias_v);
            pkv.w = f2b(acc[2][i][j][3] + bias_v);
            size_t frag = ((size_t)(bb * NH + h) * NKB + kbi) * 8 + hb * 4 + i;
            *reinterpret_cast<ushort4*>(
                &Vf[frag * 512 + (halfv * 32 + l31v) * 8 + j0]) = pkv;
        }
    }
}

// Output projection: 128x64 tiles, grid (64, 12) = 768 blocks = 3 WG/CU even.
__global__ __launch_bounds__(256, 3) void gemm_o(
    const unsigned short* __restrict__ A,
    const unsigned short* __restrict__ W,
    const float* __restrict__ bias,
    float* __restrict__ out)
{
    __shared__ __align__(16) unsigned short As[128 * 64];   // 16 KB
    __shared__ __align__(16) unsigned short Bs[64 * 64];    // 8 KB

    const int tid  = threadIdx.x;
    const int w    = tid >> 6, lane = tid & 63;
    const int quad = lane >> 4, l16 = lane & 15;
    const int wm   = w & 1,  wn = w >> 1;
    const int lane8 = lane >> 3, sc = lane & 7;
    const int m0  = blockIdx.x * 128;
    const int n0l = blockIdx.y * 64;

    v4f acc[4][2];
    #pragma unroll
    for (int i = 0; i < 4; ++i)
        #pragma unroll
        for (int j = 0; j < 2; ++j)
            acc[i][j] = v4f{0.f, 0.f, 0.f, 0.f};

    for (int kb = 0; kb < DIM; kb += 64) {
        __syncthreads();
        #pragma unroll
        for (int t = 0; t < 4; ++t) {
            int r8 = w * 32 + t * 8;
            int r  = r8 + lane8;
            int gch = sc ^ (r & 7);
            g2l16(&A[(size_t)(m0 + r) * DIM + kb + gch * 8], &As[r8 * 64]);
        }
        #pragma unroll
        for (int t = 0; t < 2; ++t) {
            int r8 = (w * 2 + t) * 8;
            int r  = r8 + lane8;
            int gch = sc ^ (r & 7);
            g2l16(&W[(size_t)(n0l + r) * DIM + kb + gch * 8], &Bs[r8 * 64]);
        }
        __syncthreads();
        #pragma unroll
        for (int kk = 0; kk < 64; kk += 32) {
            v8s a[4], b[2];
            int chb = kk >> 3;
            #pragma unroll
            for (int i = 0; i < 4; ++i) {
                int m = wm * 64 + i * 16 + l16;
                a[i] = *reinterpret_cast<const v8s*>(
                    &As[m * 64 + (((chb + quad) ^ (m & 7)) << 3)]);
            }
            #pragma unroll
            for (int j = 0; j < 2; ++j) {
                int n = wn * 32 + j * 16 + l16;
                b[j] = *reinterpret_cast<const v8s*>(
                    &Bs[n * 64 + (((chb + quad) ^ (n & 7)) << 3)]);
            }
            #pragma unroll
            for (int i = 0; i < 4; ++i)
                #pragma unroll
                for (int j = 0; j < 2; ++j)
                    acc[i][j] = __builtin_amdgcn_mfma_f32_16x16x32_bf16(a[i], b[j], acc[i][j], 0, 0, 0);
        }
    }

    #pragma unroll
    for (int i = 0; i < 4; ++i) {
        #pragma unroll
        for (int j = 0; j < 2; ++j) {
            int gn = n0l + wn * 32 + j * 16 + l16;
            float bias_v = bias[gn];
            #pragma unroll
            for (int r = 0; r < 4; ++r) {
                int gm = m0 + wm * 64 + i * 16 + quad * 4 + r;
                out[(size_t)gm * DIM + gn] = acc[i][j][r] + bias_v;
            }
        }
    }
}

// ---------------------------------------------------------------------------
// Transposed flash attention (best verified structure, 66-67us, absmax
// 4.88e-4): LDS double-buffer for both K and V staged once per block via
// global_load_lds (kills the 4x redundant per-wave L2 streams: 22 TB/s ->
// 5.6 TB/s aggregate), one plain __syncthreads per tile, permlane32_swap
// partner exchange (replaces 8 ds_bpermute + 24 selects per tile),
// split PV accumulators (halved dependent-chain depth), cvtpk packing,
// XCD-swizzled blockIdx (K/V L2-resident: FETCH 18.5 MB).
// Plateaued at the 3-wave/SIMD interleave limit.
// ---------------------------------------------------------------------------
__global__ __launch_bounds__(256, 3) void attn(
    const unsigned short* __restrict__ Q,
    const unsigned short* __restrict__ Kf,
    const unsigned short* __restrict__ Vf,
    unsigned short* __restrict__ ctx)
{
    __shared__ __align__(16) unsigned short Ks[2][8 * 512];   // 16 KB
    __shared__ __align__(16) unsigned short Vs[2][8 * 512];   // 16 KB

    const int tid  = threadIdx.x;
    const int w    = tid >> 6, lane = tid & 63;
    const int l31  = lane & 31, half = lane >> 5;

    // XCD swizzle: 768 blocks, 8 XCDs -> XCD k owns bh [6k, 6k+6) x 16 q-tiles
    const int lblk = blockIdx.y * 16 + blockIdx.x;       // gridDim.x == 16
    const int vblk = (lblk & 7) * 96 + (lblk >> 3);
    const int bh   = vblk >> 4;
    const int b    = bh / NH, h = bh % NH;
    const int q0   = (vblk & 15) * 128 + w * 32;

    const unsigned short* Qp = Q  + ((size_t)bh * SEQ + q0) * HD;
    const unsigned short* Kh = Kf + (size_t)bh * (NKB * 8 * 512);
    const unsigned short* Vh = Vf + (size_t)bh * (NKB * 8 * 512);

    // Q B-frag: B[n=q=l31][k = c*16 + half*8 + j] (pre-scaled by 0.125*log2e)
    v8s bq[4];
    #pragma unroll
    for (int c = 0; c < 4; ++c)
        bq[c] = *reinterpret_cast<const v8s*>(&Qp[l31 * HD + c * 16 + half * 8]);

    // wave w stages K frags {2w, 2w+1} and V frags {2w, 2w+1} of each tile
    #define STAGE(it_, buf_)                                                   \
        do {                                                                   \
            _Pragma("unroll")                                                  \
            for (int t = 0; t < 2; ++t) {                                      \
                int g = w * 2 + t;                                             \
                g2l16(&Kh[((size_t)(it_) * 8 + g) * 512 + lane * 8],           \
                      &Ks[buf_][g * 512]);                                     \
                g2l16(&Vh[((size_t)(it_) * 8 + g) * 512 + lane * 8],           \
                      &Vs[buf_][g * 512]);                                     \
            }                                                                  \
        } while (0)

    STAGE(0, 0);

    v16f o0a, o0b, o1a, o1b, Z;
    #pragma unroll
    for (int i = 0; i < 16; ++i) {
        o0a[i] = 0.f; o0b[i] = 0.f; o1a[i] = 0.f; o1b[i] = 0.f; Z[i] = 0.f;
    }
    float li = 0.f;

    int cur = 0;
    for (int it = 0; it < NKB; ++it) {
        __syncthreads();                       // certifies STAGE(it) block-wide
        if (it + 1 < NKB) STAGE(it + 1, cur ^ 1);

        const unsigned short* Kb_ = Ks[cur];
        const unsigned short* Vb_ = Vs[cur];

        // S^T[key][q]: two independent 4-deep MFMA chains (keys 0..31 / 32..63)
        v16f s0, s1;
        {
            v8s k0 = *reinterpret_cast<const v8s*>(&Kb_[lane * 8]);
            v8s k1 = *reinterpret_cast<const v8s*>(&Kb_[4 * 512 + lane * 8]);
            s0 = __builtin_amdgcn_mfma_f32_32x32x16_bf16(k0, bq[0], Z, 0, 0, 0);
            s1 = __builtin_amdgcn_mfma_f32_32x32x16_bf16(k1, bq[0], Z, 0, 0, 0);
            #pragma unroll
            for (int c = 1; c < 4; ++c) {
                v8s kc0 = *reinterpret_cast<const v8s*>(&Kb_[(size_t)c * 512 + lane * 8]);
                v8s kc1 = *reinterpret_cast<const v8s*>(&Kb_[(size_t)(4 + c) * 512 + lane * 8]);
                s0 = __builtin_amdgcn_mfma_f32_32x32x16_bf16(kc0, bq[c], s0, 0, 0, 0);
                s1 = __builtin_amdgcn_mfma_f32_32x32x16_bf16(kc1, bq[c], s1, 0, 0, 0);
            }
        }

        // exp2 + lane-local li + pack key-pairs (1 instr per pair via cvt_pk)
        unsigned pk[8][2];
        #pragma unroll
        for (int g = 0; g < 4; ++g) {
            float e0 = EXP2(s0[4*g+0]), e1 = EXP2(s0[4*g+1]);
            float e2 = EXP2(s0[4*g+2]), e3 = EXP2(s0[4*g+3]);
            li += (e0 + e1) + (e2 + e3);
            pk[g][0] = cvtpk(e0, e1);
            pk[g][1] = cvtpk(e2, e3);
            float f0 = EXP2(s1[4*g+0]), f1 = EXP2(s1[4*g+1]);
            float f2 = EXP2(s1[4*g+2]), f3 = EXP2(s1[4*g+3]);
            li += (f0 + f1) + (f2 + f3);
            pk[4+g][0] = cvtpk(f0, f1);
            pk[4+g][1] = cvtpk(f2, f3);
        }

        // P^T B-frags via v_permlane32_swap_b32 (R8-verified); V from LDS.
        #pragma unroll
        for (int cp = 0; cp < 4; ++cp) {
            unsigned a0 = pk[2*cp][0],   a1 = pk[2*cp][1];
            unsigned b0 = pk[2*cp+1][0], b1 = pk[2*cp+1][1];
            asm("v_permlane32_swap_b32 %0, %1" : "+v"(a0), "+v"(b0));
            asm("v_permlane32_swap_b32 %0, %1" : "+v"(a1), "+v"(b1));
            v4u fw;
            fw.x = a0; fw.y = a1; fw.z = b0; fw.w = b1;
            v8s pf = __builtin_bit_cast(v8s, fw);
            v8s v0 = *reinterpret_cast<const v8s*>(&Vb_[(size_t)cp * 512 + lane * 8]);
            v8s v1 = *reinterpret_cast<const v8s*>(&Vb_[(size_t)(4 + cp) * 512 + lane * 8]);
            if (cp < 2) {
                o0a = __builtin_amdgcn_mfma_f32_32x32x16_bf16(v0, pf, o0a, 0, 0, 0);
                o1a = __builtin_amdgcn_mfma_f32_32x32x16_bf16(v1, pf, o1a, 0, 0, 0);
            } else {
                o0b = __builtin_amdgcn_mfma_f32_32x32x16_bf16(v0, pf, o0b, 0, 0, 0);
                o1b = __builtin_amdgcn_mfma_f32_32x32x16_bf16(v1, pf, o1b, 0, 0, 0);
            }
        }

        cur ^= 1;
    }
    #undef STAGE

    // li total = own 32 keys + partner's 32 keys (same q)
    float inv = 1.0f / (li + __shfl_xor(li, 32));

    // O^T: lane holds q = q0+l31; rows hd = (reg&3)+8*(reg>>2)+4*half (+32 for o1)
    const int q = q0 + l31;
    size_t base = ((size_t)(b * SEQ + q)) * DIM + h * HD;
    #pragma unroll
    for (int g = 0; g < 4; ++g) {
        int hd0 = 8 * g + 4 * half;
        uint2 u0, u1;
        u0.x = cvtpk((o0a[4*g+0] + o0b[4*g+0]) * inv, (o0a[4*g+1] + o0b[4*g+1]) * inv);
        u0.y = cvtpk((o0a[4*g+2] + o0b[4*g+2]) * inv, (o0a[4*g+3] + o0b[4*g+3]) * inv);
        u1.x = cvtpk((o1a[4*g+0] + o1b[4*g+0]) * inv, (o1a[4*g+1] + o1b[4*g+1]) * inv);
        u1.y = cvtpk((o1a[4*g+2] + o1b[4*g+2]) * inv, (o1a[4*g+3] + o1b[4*g+3]) * inv);
        *reinterpret_cast<uint2*>(&ctx[base + hd0])      = u0;
        *reinterpret_cast<uint2*>(&ctx[base + 32 + hd0]) = u1;
    }
}

extern "C" void kernel_launch(void* const* d_in, const int* in_sizes, int n_in,
                              void* d_out, int out_size, void* d_ws, size_t ws_size,
                              hipStream_t stream) {
    const float* x  = (const float*)d_in[0];
    const float* qw = (const float*)d_in[1]; const float* qb = (const float*)d_in[2];
    const float* kw = (const float*)d_in[3]; const float* kb = (const float*)d_in[4];
    const float* vw = (const float*)d_in[5]; const float* vb = (const float*)d_in[6];
    const float* ow = (const float*)d_in[7]; const float* ob = (const float*)d_in[8];
    float* out = (float*)d_out;

    char* ws = (char*)d_ws;
    size_t off = 0;
    auto alloc = [&](size_t bytes) -> unsigned short* {
        unsigned short* p = (unsigned short*)(ws + off);
        off += (bytes + 255) & ~(size_t)255;
        return p;
    };
    const size_t XB = (size_t)MM * DIM * 2;
    const size_t WB = (size_t)DIM * DIM * 2;
    const size_t QB = (size_t)NB * NH * SEQ * HD * 2;

    unsigned short* xb  = alloc(XB);
    unsigned short* wqb = alloc(WB);
    unsigned short* wkb = alloc(WB);
    unsigned short* wvb = alloc(WB);
    unsigned short* wob = alloc(WB);
    unsigned short* Qb  = alloc(QB);
    unsigned short* Kfb = alloc(QB);   // fragment-native K
    unsigned short* Vfb = alloc(QB);   // fragment-native V
    unsigned short* ctx = alloc(XB);

    const int nitems = N4X + 4 * N4W;            // 2162688, /256 = 8448 exact
    cast_all<<<nitems / 256, 256, 0, stream>>>(
        x, qw, kw, vw, ow, xb, wqb, wkb, wvb, wob);

    gemm_qkv<<<dim3(MM / 128, NH), 256, 0, stream>>>(
        xb, wqb, wkb, wvb, qb, kb, vb, Qb, Kfb, Vfb);

    attn<<<dim3(SEQ / 128, NB * NH), 256, 0, stream>>>(Qb, Kfb, Vfb, ctx);

    gemm_o<<<dim3(MM / 128, DIM / 64), 256, 0, stream>>>(ctx, wob, ob, out);
}